// Round 13
// baseline (351.561 us; speedup 1.0000x reference)
//
#include <hip/hip_runtime.h>
#include <stdint.h>

typedef __attribute__((ext_vector_type(8))) short short8;
typedef __attribute__((ext_vector_type(4))) float f32x4;

#define NNODES 55296
#define DOUT 256

#define WAIT_VM(N) asm volatile("s_waitcnt vmcnt(" #N ")" ::: "memory")
#define WAIT_LGKM0 asm volatile("s_waitcnt lgkmcnt(0)" ::: "memory")
#define SOFT_FENCE asm volatile("" ::: "memory")

__device__ __forceinline__ float bf2f(unsigned short h) {
    union { unsigned u; float f; } x; x.u = ((unsigned)h) << 16; return x.f;
}
__device__ __forceinline__ unsigned short f2bf(float f) {
    union { float f; unsigned u; } x; x.f = f;
    return (unsigned short)((x.u + 0x7fffu + ((x.u >> 16) & 1u)) >> 16);
}

__device__ __forceinline__ void storev(float* p, float v) { *p = v; }
__device__ __forceinline__ void storev(unsigned short* p, float v) { *p = f2bf(v); }

__device__ __forceinline__ void dma16(const void* g, void* l) {
    __builtin_amdgcn_global_load_lds(
        reinterpret_cast<const unsigned int __attribute__((address_space(1)))*>((uintptr_t)g),
        reinterpret_cast<unsigned int __attribute__((address_space(3)))*>((uintptr_t)l),
        16, 0, 0);
}

// ---- fragment helpers (v3 fallback + mean kernels) ----
__device__ __forceinline__ short8 frag_self(const float* p) {
    float4 a = *(const float4*)p, b = *(const float4*)(p + 4);
    union { short8 s; unsigned short u[8]; } r;
    r.u[0] = f2bf(a.x); r.u[1] = f2bf(a.y); r.u[2] = f2bf(a.z); r.u[3] = f2bf(a.w);
    r.u[4] = f2bf(b.x); r.u[5] = f2bf(b.y); r.u[6] = f2bf(b.z); r.u[7] = f2bf(b.w);
    return r.s;
}
__device__ __forceinline__ short8 frag_self(const unsigned short* p) {
    return *(const short8*)p;
}
__device__ __forceinline__ void acc8(const float* p, float* o) {
    float4 a = *(const float4*)p, b = *(const float4*)(p + 4);
    o[0] += a.x; o[1] += a.y; o[2] += a.z; o[3] += a.w;
    o[4] += b.x; o[5] += b.y; o[6] += b.z; o[7] += b.w;
}
__device__ __forceinline__ void acc8(const unsigned short* p, float* o) {
    uint4 v = *(const uint4*)p;
    const unsigned short* u = (const unsigned short*)&v;
#pragma unroll
    for (int i = 0; i < 8; ++i) o[i] += bf2f(u[i]);
}
template <typename TIN>
__device__ __forceinline__ short8 frag_mean4(const TIN* p0, const TIN* p1,
                                             const TIN* p2, const TIN* p3) {
    float s[8] = {0.f, 0.f, 0.f, 0.f, 0.f, 0.f, 0.f, 0.f};
    acc8(p0, s); acc8(p1, s); acc8(p2, s); acc8(p3, s);
    union { short8 s8; unsigned short u[8]; } r;
#pragma unroll
    for (int i = 0; i < 8; ++i) r.u[i] = f2bf(s[i] * 0.25f);
    return r.s8;
}

// Wt[d][k] = bf16( k < C ? W_self[k][d] : W_neigh[k-C][d] )
__global__ void build_wt(const float* __restrict__ Ws,
                         const float* __restrict__ Wn,
                         unsigned short* __restrict__ Wt, int C) {
    int K2 = 2 * C;
    int idx = blockIdx.x * 256 + threadIdx.x;
    if (idx >= 256 * K2) return;
    int d = idx / K2;
    int k = idx - d * K2;
    float v = (k < C) ? Ws[(size_t)k * DOUT + d] : Wn[(size_t)(k - C) * DOUT + d];
    Wt[idx] = f2bf(v);
}

// ---- layer-1 prep: xm[node] = [ bf16(x[node]) (128) | mean4 neighbors (128) ] ----
__global__ __launch_bounds__(256) void mean_xb(const float* __restrict__ x,
                                               const int* __restrict__ nbr,
                                               unsigned short* __restrict__ xm) {
    const int idx = blockIdx.x * 256 + threadIdx.x;
    const int node = idx >> 4;
    const int ch = (idx & 15) * 8;
    const int b = node / NNODES;
    const int n = node - b * NNODES;
    const size_t bbase = (size_t)b * NNODES;
    const int4 nb = *(const int4*)(nbr + (size_t)n * 4);
    const float* ps = x + (size_t)node * 128 + ch;
    union { uint4 v; unsigned short u[8]; } rs, rm;
    float4 a0 = *(const float4*)ps, a1 = *(const float4*)(ps + 4);
    rs.u[0] = f2bf(a0.x); rs.u[1] = f2bf(a0.y); rs.u[2] = f2bf(a0.z); rs.u[3] = f2bf(a0.w);
    rs.u[4] = f2bf(a1.x); rs.u[5] = f2bf(a1.y); rs.u[6] = f2bf(a1.z); rs.u[7] = f2bf(a1.w);
    float s[8] = {0.f, 0.f, 0.f, 0.f, 0.f, 0.f, 0.f, 0.f};
    acc8(x + (bbase + nb.x) * 128 + ch, s);
    acc8(x + (bbase + nb.y) * 128 + ch, s);
    acc8(x + (bbase + nb.z) * 128 + ch, s);
    acc8(x + (bbase + nb.w) * 128 + ch, s);
#pragma unroll
    for (int i = 0; i < 8; ++i) rm.u[i] = f2bf(s[i] * 0.25f);
    *(uint4*)(xm + (size_t)node * 256 + ch) = rs.v;
    *(uint4*)(xm + (size_t)node * 256 + 128 + ch) = rm.v;
}

// ---- hm2[node][c] = bf16(mean of 4 neighbors of h1) ----
template <int C, typename TIN>
__global__ __launch_bounds__(256) void mean_pass(const TIN* __restrict__ hin,
                                                 const int* __restrict__ nbr,
                                                 unsigned short* __restrict__ hm) {
    constexpr int CPL = C / 8;
    const int idx = blockIdx.x * 256 + threadIdx.x;
    const int node = idx / CPL;
    const int ch = (idx - node * CPL) * 8;
    const int b = node / NNODES;
    const int n = node - b * NNODES;
    const size_t bbase = (size_t)b * NNODES;
    const int4 nb = *(const int4*)(nbr + (size_t)n * 4);
    float s[8] = {0.f, 0.f, 0.f, 0.f, 0.f, 0.f, 0.f, 0.f};
    acc8(hin + (bbase + nb.x) * (size_t)C + ch, s);
    acc8(hin + (bbase + nb.y) * (size_t)C + ch, s);
    acc8(hin + (bbase + nb.z) * (size_t)C + ch, s);
    acc8(hin + (bbase + nb.w) * (size_t)C + ch, s);
    union { uint4 v; unsigned short u[8]; } r;
#pragma unroll
    for (int i = 0; i < 8; ++i) r.u[i] = f2bf(s[i] * 0.25f);
    *(uint4*)(hm + (size_t)node * C + ch) = r.v;
}

// ============================================================================
// v12: 4-wave blocks (256 thr), tile 128 rows x 128 cols, 56KB LDS
// (W 32KB single-buffer restaged + A-ring 3x8KB) -> 2 independent blocks/CU.
// XCD-chunked bijective swizzle keeps the yg col-half pair (same A rows) on
// one XCD's L2. A-layout [cj][kslot][row] conflict-free; W lr-XOR swizzled.
// vmcnt(2) steady / 0 at end; W restage at (kk&3)==3. MFMA swapped (wf, af).
// ============================================================================
template <int NK, typename TOUT>
__global__ __launch_bounds__(256) void sage_v12(
    const unsigned short* __restrict__ h1p,   // A source, phases [0,8)
    const unsigned short* __restrict__ hmp,   // A source, phases [8,16) (L2)
    const unsigned short* __restrict__ Wt,    // [256 d][NK*32 k] bf16
    const float* __restrict__ bias,           // [256]
    TOUT* __restrict__ out,                   // [M][256]
    int nwg) {
    extern __shared__ char lds[];
    constexpr int WB = NK * 64;               // W row bytes (512 / 1024)
    const int tid = threadIdx.x;
    // XCD-chunked bijective swizzle (nwg % 8 == 0)
    const int bid = blockIdx.x;
    const int wk = (bid & 7) * (nwg >> 3) + (bid >> 3);
    const int yg = wk & 1;
    const int rb = wk >> 1;
    const int gcol0 = yg * 128;
    const int rowbase = rb * 128;

    const int l = tid & 63, w = tid >> 6;
    const int lr = l & 15, lg = l >> 4;
    const int rowg = w >> 1;          // 2 row groups x 64 rows
    const int colb = (w & 1) * 64;    // 2 col groups x 64 cols

    const char* wsrc = (const char*)Wt + (size_t)gcol0 * WB;

    auto stageW = [&](int s) {  // 32KB: 128 cols x 256B k-stage; src pre-swizzled
#pragma unroll
        for (int i = 0; i < 8; ++i) {
            int o = w * 1024 + i * 4096 + l * 16;
            int col = o >> 8, kq = o & 255;
            dma16(wsrc + (unsigned)(col * WB + s * 256 + (kq ^ ((col & 7) << 4))),
                  lds + w * 1024 + i * 4096);
        }
    };
    auto issueA = [&](int p) {  // 8KB buf: [cj(8)][ksl(4)][rlow(16)] x 16B
        const char* base = (NK == 16 && p >= 8) ? (const char*)hmp : (const char*)h1p;
        const unsigned kb = (unsigned)(p & 7) * 64;
        char* ring = lds + 32768 + (p % 3) * 8192;
#pragma unroll
        for (int i = 0; i < 2; ++i) {
            const int cj = w + i * 4;
            const int row = rowbase + cj * 16 + lr;
            dma16(base + ((unsigned)row * 512 + kb + (unsigned)(lg << 4)),
                  ring + cj * 1024);
        }
    };

    issueA(0); stageW(0); issueA(1);

    f32x4 acc[4][4];
#pragma unroll
    for (int m = 0; m < 4; ++m)
#pragma unroll
        for (int j = 0; j < 4; ++j) acc[m][j] = (f32x4){0.f, 0.f, 0.f, 0.f};

    // af: per-m contiguous 1KB at (rowg*4+m)*1024 + l*16
    const int abase = rowg * 4096 + lg * 256 + lr * 16;
    const int wbase = (colb + lr) << 8;

#pragma unroll
    for (int kk = 0; kk < NK; ++kk) {
        if (kk == NK - 1) { WAIT_VM(0); } else { WAIT_VM(2); }
        __builtin_amdgcn_s_barrier();
        SOFT_FENCE;

        const int bufo = 32768 + (kk % 3) * 8192;
        short8 af[4];
#pragma unroll
        for (int m = 0; m < 4; ++m)
            af[m] = *(const short8*)(lds + bufo + abase + m * 1024);

#pragma unroll
        for (int j = 0; j < 4; ++j) {
            const short8 wf = *(const short8*)(
                lds + wbase + (j << 12) +
                ((((kk & 3) << 6) | (lg << 4)) ^ ((lr & 7) << 4)));
#pragma unroll
            for (int m = 0; m < 4; ++m)
                acc[m][j] = __builtin_amdgcn_mfma_f32_16x16x32_bf16(wf, af[m], acc[m][j], 0, 0, 0);
        }

        if ((kk & 3) == 3 && kk < NK - 1) {  // restage next 256B W k-stage
            WAIT_LGKM0;
            __builtin_amdgcn_sched_barrier(0);
            __builtin_amdgcn_s_barrier();
            stageW((kk >> 2) + 1);
        }
        if (kk + 2 < NK) issueA(kk + 2);
        SOFT_FENCE;
    }

    // epilogue (swapped layout): 4 consecutive cols per lane, packed stores
#pragma unroll
    for (int m = 0; m < 4; ++m) {
        const int row = rowbase + rowg * 64 + m * 16 + lr;
#pragma unroll
        for (int j = 0; j < 4; ++j) {
            const int gcol = gcol0 + colb + j * 16 + lg * 4;
            const float4 bv = *(const float4*)(bias + gcol);
            float o0 = fmaxf(acc[m][j][0] + bv.x, 0.f);
            float o1 = fmaxf(acc[m][j][1] + bv.y, 0.f);
            float o2 = fmaxf(acc[m][j][2] + bv.z, 0.f);
            float o3 = fmaxf(acc[m][j][3] + bv.w, 0.f);
            if constexpr (sizeof(TOUT) == 4) {
                float4 o = {o0, o1, o2, o3};
                *(float4*)((float*)out + (size_t)row * 256 + gcol) = o;
            } else {
                union { unsigned short u[4]; uint2 v; } pk;
                pk.u[0] = f2bf(o0); pk.u[1] = f2bf(o1);
                pk.u[2] = f2bf(o2); pk.u[3] = f2bf(o3);
                *(uint2*)((unsigned short*)out + (size_t)row * 256 + gcol) = pk.v;
            }
        }
    }
}

// ---- v3 fallback (small ws): fused gather, weights all-K in LDS ----
template <int C, typename TIN, typename TOUT>
__global__ __launch_bounds__(512, 2) void sage_v3(
    const TIN* __restrict__ hin, const int* __restrict__ nbr,
    const unsigned short* __restrict__ Wt, const float* __restrict__ bias,
    TOUT* __restrict__ out) {
    constexpr int K2 = 2 * C;
    constexpr int ROWB = K2 * 2;
    constexpr int LCOLS = 131072 / ROWB;
    constexpr int CG = LCOLS / 128;
    constexpr int RG = 8 / CG;
    extern __shared__ char Bs[];

    const int tid = threadIdx.x;
    const int gcol0 = blockIdx.y * LCOLS;
    {
        const char* src = (const char*)(Wt + (size_t)gcol0 * K2);
#pragma unroll
        for (int i = 0; i < 16; ++i) {
            int byt = (i * 512 + tid) * 16;
            uint4 v = *(const uint4*)(src + byt);
            int c = byt / ROWB;
            *(uint4*)(Bs + (byt ^ ((c & 7) << 4))) = v;
        }
    }
    __syncthreads();

    const int l = tid & 63;
    const int w = tid >> 6;
    const int rowg = w / CG;
    const int colb = (w % CG) * 128;
    const int lr = l & 15, lg = l >> 4;

    const int rowbase = blockIdx.x * (RG * 64) + rowg * 64;
    const int bb = rowbase / NNODES;
    const int n0 = rowbase - bb * NNODES;
    const size_t bbase = (size_t)bb * NNODES;

    unsigned soff[4], noff[4][4];
#pragma unroll
    for (int m = 0; m < 4; ++m) {
        int r = m * 16 + lr;
        soff[m] = (unsigned)(((rowbase + r) * (size_t)C + lg * 8) * sizeof(TIN));
        int4 nb = *(const int4*)(nbr + (size_t)(n0 + r) * 4);
        noff[m][0] = (unsigned)(((bbase + nb.x) * C + lg * 8) * sizeof(TIN));
        noff[m][1] = (unsigned)(((bbase + nb.y) * C + lg * 8) * sizeof(TIN));
        noff[m][2] = (unsigned)(((bbase + nb.z) * C + lg * 8) * sizeof(TIN));
        noff[m][3] = (unsigned)(((bbase + nb.w) * C + lg * 8) * sizeof(TIN));
    }
    const char* hb = (const char*)hin;

    f32x4 acc[4][8];
#pragma unroll
    for (int m = 0; m < 4; ++m)
#pragma unroll
        for (int j = 0; j < 8; ++j) acc[m][j] = (f32x4){0.f, 0.f, 0.f, 0.f};

#pragma unroll
    for (int kk = 0; kk < K2 / 32; ++kk) {
        const int k0 = kk * 32;
        short8 a[4];
        if (k0 < C) {
            const unsigned kb = k0 * sizeof(TIN);
#pragma unroll
            for (int m = 0; m < 4; ++m)
                a[m] = frag_self((const TIN*)(hb + soff[m] + kb));
        } else {
            const unsigned kb = (k0 - C) * sizeof(TIN);
#pragma unroll
            for (int m = 0; m < 4; ++m)
                a[m] = frag_mean4((const TIN*)(hb + noff[m][0] + kb),
                                  (const TIN*)(hb + noff[m][1] + kb),
                                  (const TIN*)(hb + noff[m][2] + kb),
                                  (const TIN*)(hb + noff[m][3] + kb));
        }
#pragma unroll
        for (int j = 0; j < 8; ++j) {
            const int c = colb + j * 16 + lr;
            const short8 bf = *(const short8*)(
                Bs + ((c * ROWB + (k0 + lg * 8) * 2) ^ ((l & 7) << 4)));
#pragma unroll
            for (int m = 0; m < 4; ++m)
                acc[m][j] = __builtin_amdgcn_mfma_f32_16x16x32_bf16(a[m], bf, acc[m][j], 0, 0, 0);
        }
    }

#pragma unroll
    for (int j = 0; j < 8; ++j) {
        const int gcol = gcol0 + colb + j * 16 + lr;
        const float bv = bias[gcol];
#pragma unroll
        for (int m = 0; m < 4; ++m) {
#pragma unroll
            for (int r = 0; r < 4; ++r) {
                const int row = rowbase + m * 16 + lg * 4 + r;
                storev(out + (size_t)row * DOUT + gcol, fmaxf(acc[m][j][r] + bv, 0.f));
            }
        }
    }
}

extern "C" void kernel_launch(void* const* d_in, const int* in_sizes, int n_in,
                              void* d_out, int out_size, void* d_ws, size_t ws_size,
                              hipStream_t stream) {
    const float* x = (const float*)d_in[0];
    const int* nbr = (const int*)d_in[1];
    const float* Ws1 = (const float*)d_in[2];
    const float* Wn1 = (const float*)d_in[3];
    const float* b1 = (const float*)d_in[4];
    const float* Ws2 = (const float*)d_in[5];
    const float* Wn2 = (const float*)d_in[6];
    const float* b2 = (const float*)d_in[7];
    float* out = (float*)d_out;

    const int B = in_sizes[0] / (NNODES * 128);  // 4
    const int M = B * NNODES;                    // 221184

    char* ws = (char*)d_ws;
    const size_t h1_bytes = (size_t)M * DOUT * 2;
    const size_t hm_bytes = (size_t)M * DOUT * 2;  // xm for L1, then hm2 for L2
    const size_t need = h1_bytes + hm_bytes + 131072 + 262144;

    if (ws_size >= need) {
        unsigned short* h1 = (unsigned short*)ws;
        unsigned short* xm = (unsigned short*)(ws + h1_bytes);  // reused as hm2
        unsigned short* Wt1 = (unsigned short*)(ws + h1_bytes + hm_bytes);
        unsigned short* Wt2 = Wt1 + 256 * 256;

        build_wt<<<256, 256, 0, stream>>>(Ws1, Wn1, Wt1, 128);
        build_wt<<<512, 256, 0, stream>>>(Ws2, Wn2, Wt2, 256);

        hipFuncSetAttribute((const void*)sage_v12<8, unsigned short>,
                            hipFuncAttributeMaxDynamicSharedMemorySize, 57344);
        hipFuncSetAttribute((const void*)sage_v12<16, float>,
                            hipFuncAttributeMaxDynamicSharedMemorySize, 57344);

        const int nwg = (M / 128) * 2;  // 3456, divisible by 8

        // layer 1: xm = [bf16(x) | mean4(x)]; K2=256
        mean_xb<<<M / 16, 256, 0, stream>>>(x, nbr, xm);
        sage_v12<8, unsigned short>
            <<<nwg, 256, 57344, stream>>>(xm, xm, Wt1, b1, h1, nwg);
        // layer 2: hm2 overwrites xm; K2=512, A = h1 then hm
        mean_pass<256, unsigned short><<<M * 32 / 256, 256, 0, stream>>>(h1, nbr, xm);
        sage_v12<16, float>
            <<<nwg, 256, 57344, stream>>>(h1, xm, Wt2, b2, out, nwg);
    } else {
        unsigned short* h1 = (unsigned short*)ws;
        unsigned short* Wt1 = (unsigned short*)(ws + h1_bytes);
        unsigned short* Wt2 = Wt1 + 256 * 256;

        build_wt<<<256, 256, 0, stream>>>(Ws1, Wn1, Wt1, 128);
        build_wt<<<512, 256, 0, stream>>>(Ws2, Wn2, Wt2, 256);

        hipFuncSetAttribute((const void*)sage_v3<128, float, unsigned short>,
                            hipFuncAttributeMaxDynamicSharedMemorySize, 131072);
        hipFuncSetAttribute((const void*)sage_v3<256, unsigned short, float>,
                            hipFuncAttributeMaxDynamicSharedMemorySize, 131072);

        sage_v3<128, float, unsigned short>
            <<<dim3(M / 256, 1), 512, 131072, stream>>>(x, nbr, Wt1, b1, h1);
        sage_v3<256, unsigned short, float>
            <<<dim3(M / 512, 2), 512, 131072, stream>>>(h1, nbr, Wt2, b2, out);
    }
}

// Round 14
// 346.119 us; speedup vs baseline: 1.0157x; 1.0157x over previous
//
#include <hip/hip_runtime.h>
#include <stdint.h>

typedef __attribute__((ext_vector_type(8))) short short8;
typedef __attribute__((ext_vector_type(4))) float f32x4;

#define NNODES 55296
#define DOUT 256

#define WAIT_VM(N) asm volatile("s_waitcnt vmcnt(" #N ")" ::: "memory")
#define SOFT_FENCE asm volatile("" ::: "memory")

__device__ __forceinline__ float bf2f(unsigned short h) {
    union { unsigned u; float f; } x; x.u = ((unsigned)h) << 16; return x.f;
}
__device__ __forceinline__ unsigned short f2bf(float f) {
    union { float f; unsigned u; } x; x.f = f;
    return (unsigned short)((x.u + 0x7fffu + ((x.u >> 16) & 1u)) >> 16);
}

__device__ __forceinline__ void storev(float* p, float v) { *p = v; }
__device__ __forceinline__ void storev(unsigned short* p, float v) { *p = f2bf(v); }

__device__ __forceinline__ void dma16(const void* g, void* l) {
    __builtin_amdgcn_global_load_lds(
        reinterpret_cast<const unsigned int __attribute__((address_space(1)))*>((uintptr_t)g),
        reinterpret_cast<unsigned int __attribute__((address_space(3)))*>((uintptr_t)l),
        16, 0, 0);
}

// ---- fragment helpers (v3 fallback + mean kernels) ----
__device__ __forceinline__ short8 frag_self(const float* p) {
    float4 a = *(const float4*)p, b = *(const float4*)(p + 4);
    union { short8 s; unsigned short u[8]; } r;
    r.u[0] = f2bf(a.x); r.u[1] = f2bf(a.y); r.u[2] = f2bf(a.z); r.u[3] = f2bf(a.w);
    r.u[4] = f2bf(b.x); r.u[5] = f2bf(b.y); r.u[6] = f2bf(b.z); r.u[7] = f2bf(b.w);
    return r.s;
}
__device__ __forceinline__ short8 frag_self(const unsigned short* p) {
    return *(const short8*)p;
}
__device__ __forceinline__ void acc8(const float* p, float* o) {
    float4 a = *(const float4*)p, b = *(const float4*)(p + 4);
    o[0] += a.x; o[1] += a.y; o[2] += a.z; o[3] += a.w;
    o[4] += b.x; o[5] += b.y; o[6] += b.z; o[7] += b.w;
}
__device__ __forceinline__ void acc8(const unsigned short* p, float* o) {
    uint4 v = *(const uint4*)p;
    const unsigned short* u = (const unsigned short*)&v;
#pragma unroll
    for (int i = 0; i < 8; ++i) o[i] += bf2f(u[i]);
}
template <typename TIN>
__device__ __forceinline__ short8 frag_mean4(const TIN* p0, const TIN* p1,
                                             const TIN* p2, const TIN* p3) {
    float s[8] = {0.f, 0.f, 0.f, 0.f, 0.f, 0.f, 0.f, 0.f};
    acc8(p0, s); acc8(p1, s); acc8(p2, s); acc8(p3, s);
    union { short8 s8; unsigned short u[8]; } r;
#pragma unroll
    for (int i = 0; i < 8; ++i) r.u[i] = f2bf(s[i] * 0.25f);
    return r.s8;
}

// Wt[d][k] = bf16( k < C ? W_self[k][d] : W_neigh[k-C][d] )
__global__ void build_wt(const float* __restrict__ Ws,
                         const float* __restrict__ Wn,
                         unsigned short* __restrict__ Wt, int C) {
    int K2 = 2 * C;
    int idx = blockIdx.x * 256 + threadIdx.x;
    if (idx >= 256 * K2) return;
    int d = idx / K2;
    int k = idx - d * K2;
    float v = (k < C) ? Ws[(size_t)k * DOUT + d] : Wn[(size_t)(k - C) * DOUT + d];
    Wt[idx] = f2bf(v);
}

// ---- layer-1 prep: xm[node] = [ bf16(x[node]) (128) | mean4 neighbors (128) ] ----
__global__ __launch_bounds__(256) void mean_xb(const float* __restrict__ x,
                                               const int* __restrict__ nbr,
                                               unsigned short* __restrict__ xm) {
    const int idx = blockIdx.x * 256 + threadIdx.x;
    const int node = idx >> 4;
    const int ch = (idx & 15) * 8;
    const int b = node / NNODES;
    const int n = node - b * NNODES;
    const size_t bbase = (size_t)b * NNODES;
    const int4 nb = *(const int4*)(nbr + (size_t)n * 4);
    const float* ps = x + (size_t)node * 128 + ch;
    union { uint4 v; unsigned short u[8]; } rs, rm;
    float4 a0 = *(const float4*)ps, a1 = *(const float4*)(ps + 4);
    rs.u[0] = f2bf(a0.x); rs.u[1] = f2bf(a0.y); rs.u[2] = f2bf(a0.z); rs.u[3] = f2bf(a0.w);
    rs.u[4] = f2bf(a1.x); rs.u[5] = f2bf(a1.y); rs.u[6] = f2bf(a1.z); rs.u[7] = f2bf(a1.w);
    float s[8] = {0.f, 0.f, 0.f, 0.f, 0.f, 0.f, 0.f, 0.f};
    acc8(x + (bbase + nb.x) * 128 + ch, s);
    acc8(x + (bbase + nb.y) * 128 + ch, s);
    acc8(x + (bbase + nb.z) * 128 + ch, s);
    acc8(x + (bbase + nb.w) * 128 + ch, s);
#pragma unroll
    for (int i = 0; i < 8; ++i) rm.u[i] = f2bf(s[i] * 0.25f);
    *(uint4*)(xm + (size_t)node * 256 + ch) = rs.v;
    *(uint4*)(xm + (size_t)node * 256 + 128 + ch) = rm.v;
}

// ---- hm2[node][c] = bf16(mean of 4 neighbors of h1) ----
template <int C, typename TIN>
__global__ __launch_bounds__(256) void mean_pass(const TIN* __restrict__ hin,
                                                 const int* __restrict__ nbr,
                                                 unsigned short* __restrict__ hm) {
    constexpr int CPL = C / 8;
    const int idx = blockIdx.x * 256 + threadIdx.x;
    const int node = idx / CPL;
    const int ch = (idx - node * CPL) * 8;
    const int b = node / NNODES;
    const int n = node - b * NNODES;
    const size_t bbase = (size_t)b * NNODES;
    const int4 nb = *(const int4*)(nbr + (size_t)n * 4);
    float s[8] = {0.f, 0.f, 0.f, 0.f, 0.f, 0.f, 0.f, 0.f};
    acc8(hin + (bbase + nb.x) * (size_t)C + ch, s);
    acc8(hin + (bbase + nb.y) * (size_t)C + ch, s);
    acc8(hin + (bbase + nb.z) * (size_t)C + ch, s);
    acc8(hin + (bbase + nb.w) * (size_t)C + ch, s);
    union { uint4 v; unsigned short u[8]; } r;
#pragma unroll
    for (int i = 0; i < 8; ++i) r.u[i] = f2bf(s[i] * 0.25f);
    *(uint4*)(hm + (size_t)node * C + ch) = r.v;
}

// ============================================================================
// v13: deep pipeline. 4-wave blocks, tile 128x128, 64KB LDS -> 2 blocks/CU.
//   W: two 16KB pair-buffers (pair q = phases 2q,2q+1); pair q+1 staged at
//      START of even phase into the alt buffer (2-phase latency cover, no
//      mid-loop lgkm/barrier).
//   A: ring 4x8KB, prefetch 3 phases ahead, issued at phase start.
//   Exact counted vmcnt per phase (FIFO-derived). XCD-chunked swizzle.
//   MFMA swapped (wf, af); packed epilogue.
// ============================================================================
template <int NK, typename TOUT>
__global__ __launch_bounds__(256) void sage_v13(
    const unsigned short* __restrict__ h1p,   // A source, phases [0,8)
    const unsigned short* __restrict__ hmp,   // A source, phases [8,16) (L2)
    const unsigned short* __restrict__ Wt,    // [256 d][NK*32 k] bf16
    const float* __restrict__ bias,           // [256]
    TOUT* __restrict__ out,                   // [M][256]
    int nwg) {
    extern __shared__ char lds[];
    constexpr int WB = NK * 64;               // W row bytes (512 / 1024)
    const int tid = threadIdx.x;
    const int bid = blockIdx.x;
    const int wk = (bid & 7) * (nwg >> 3) + (bid >> 3);  // bijective (nwg%8==0)
    const int yg = wk & 1;
    const int rb = wk >> 1;
    const int gcol0 = yg * 128;
    const int rowbase = rb * 128;

    const int l = tid & 63, w = tid >> 6;
    const int lr = l & 15, lg = l >> 4;
    const int rowg = w >> 1;          // 2 row groups x 64 rows
    const int colb = (w & 1) * 64;    // 2 col groups x 64 cols

    const char* wsrc = (const char*)Wt + (size_t)gcol0 * WB;

    // stage W pair q (phases 2q,2q+1): 16KB = 128 cols x 128B; src pre-swizzled
    auto stageW = [&](int q) {
        char* wb = lds + ((q & 1) << 14);
#pragma unroll
        for (int i = 0; i < 4; ++i) {
            int o = w * 1024 + i * 4096 + l * 16;   // 0..16383
            int col = o >> 7, kq = o & 127;
            dma16(wsrc + (unsigned)(col * WB + q * 128 + (kq ^ ((col & 7) << 4))),
                  wb + o);
        }
    };
    // A ring buffer p&3 (8KB): [cj(8)][lg][lr] x 16B
    auto issueA = [&](int p) {
        const char* base = (NK == 16 && p >= 8) ? (const char*)hmp : (const char*)h1p;
        const unsigned kb = (unsigned)(p & 7) * 64;
        char* ring = lds + 32768 + (p & 3) * 8192;
#pragma unroll
        for (int i = 0; i < 2; ++i) {
            const int cj = w + i * 4;
            const int row = rowbase + cj * 16 + lr;
            dma16(base + ((unsigned)row * 512 + kb + (unsigned)(lg << 4)),
                  ring + cj * 1024);
        }
    };

    // prologue: W pair 0, A phases 0..2
    stageW(0); issueA(0); issueA(1); issueA(2);

    f32x4 acc[4][4];
#pragma unroll
    for (int m = 0; m < 4; ++m)
#pragma unroll
        for (int j = 0; j < 4; ++j) acc[m][j] = (f32x4){0.f, 0.f, 0.f, 0.f};

    const int abase = rowg * 4096 + lg * 256 + lr * 16;

#pragma unroll
    for (int kk = 0; kk < NK; ++kk) {
        // exact outstanding-count wait (FIFO-derived; see round-13 notes)
        int n;
        if (kk == 0) n = 4;
        else if (kk & 1) n = ((kk + 1 < NK) ? 6 : 0) + ((kk + 2 < NK) ? 2 : 0);
        else n = 2 + ((kk + 2 < NK) ? 2 : 0);
        switch (n) {
            case 0: WAIT_VM(0); break;
            case 2: WAIT_VM(2); break;
            case 4: WAIT_VM(4); break;
            case 6: WAIT_VM(6); break;
            default: WAIT_VM(8); break;
        }
        __builtin_amdgcn_s_barrier();
        SOFT_FENCE;

        // issue next work first (max latency cover)
        if (((kk & 1) == 0) && (kk + 2 < NK)) stageW((kk + 2) >> 1);
        if (kk + 3 < NK) issueA(kk + 3);

        const int bufo = 32768 + (kk & 3) * 8192;
        short8 af[4];
#pragma unroll
        for (int m = 0; m < 4; ++m)
            af[m] = *(const short8*)(lds + bufo + abase + m * 1024);

        char* wbuf = lds + (((kk >> 1) & 1) << 14);
        const int kq0 = ((kk & 1) << 6) | (lg << 4);
#pragma unroll
        for (int j = 0; j < 4; ++j) {
            const int col = colb + j * 16 + lr;
            const short8 wf = *(const short8*)(
                wbuf + (col << 7) + (kq0 ^ ((lr & 7) << 4)));
#pragma unroll
            for (int m = 0; m < 4; ++m)
                acc[m][j] = __builtin_amdgcn_mfma_f32_16x16x32_bf16(wf, af[m], acc[m][j], 0, 0, 0);
        }
        SOFT_FENCE;
    }

    // epilogue (swapped layout): 4 consecutive cols per lane, packed stores
#pragma unroll
    for (int m = 0; m < 4; ++m) {
        const int row = rowbase + rowg * 64 + m * 16 + lr;
#pragma unroll
        for (int j = 0; j < 4; ++j) {
            const int gcol = gcol0 + colb + j * 16 + lg * 4;
            const float4 bv = *(const float4*)(bias + gcol);
            float o0 = fmaxf(acc[m][j][0] + bv.x, 0.f);
            float o1 = fmaxf(acc[m][j][1] + bv.y, 0.f);
            float o2 = fmaxf(acc[m][j][2] + bv.z, 0.f);
            float o3 = fmaxf(acc[m][j][3] + bv.w, 0.f);
            if constexpr (sizeof(TOUT) == 4) {
                float4 o = {o0, o1, o2, o3};
                *(float4*)((float*)out + (size_t)row * 256 + gcol) = o;
            } else {
                union { unsigned short u[4]; uint2 v; } pk;
                pk.u[0] = f2bf(o0); pk.u[1] = f2bf(o1);
                pk.u[2] = f2bf(o2); pk.u[3] = f2bf(o3);
                *(uint2*)((unsigned short*)out + (size_t)row * 256 + gcol) = pk.v;
            }
        }
    }
}

// ---- v3 fallback (small ws): fused gather, weights all-K in LDS ----
template <int C, typename TIN, typename TOUT>
__global__ __launch_bounds__(512, 2) void sage_v3(
    const TIN* __restrict__ hin, const int* __restrict__ nbr,
    const unsigned short* __restrict__ Wt, const float* __restrict__ bias,
    TOUT* __restrict__ out) {
    constexpr int K2 = 2 * C;
    constexpr int ROWB = K2 * 2;
    constexpr int LCOLS = 131072 / ROWB;
    constexpr int CG = LCOLS / 128;
    constexpr int RG = 8 / CG;
    extern __shared__ char Bs[];

    const int tid = threadIdx.x;
    const int gcol0 = blockIdx.y * LCOLS;
    {
        const char* src = (const char*)(Wt + (size_t)gcol0 * K2);
#pragma unroll
        for (int i = 0; i < 16; ++i) {
            int byt = (i * 512 + tid) * 16;
            uint4 v = *(const uint4*)(src + byt);
            int c = byt / ROWB;
            *(uint4*)(Bs + (byt ^ ((c & 7) << 4))) = v;
        }
    }
    __syncthreads();

    const int l = tid & 63;
    const int w = tid >> 6;
    const int rowg = w / CG;
    const int colb = (w % CG) * 128;
    const int lr = l & 15, lg = l >> 4;

    const int rowbase = blockIdx.x * (RG * 64) + rowg * 64;
    const int bb = rowbase / NNODES;
    const int n0 = rowbase - bb * NNODES;
    const size_t bbase = (size_t)bb * NNODES;

    unsigned soff[4], noff[4][4];
#pragma unroll
    for (int m = 0; m < 4; ++m) {
        int r = m * 16 + lr;
        soff[m] = (unsigned)(((rowbase + r) * (size_t)C + lg * 8) * sizeof(TIN));
        int4 nb = *(const int4*)(nbr + (size_t)(n0 + r) * 4);
        noff[m][0] = (unsigned)(((bbase + nb.x) * C + lg * 8) * sizeof(TIN));
        noff[m][1] = (unsigned)(((bbase + nb.y) * C + lg * 8) * sizeof(TIN));
        noff[m][2] = (unsigned)(((bbase + nb.z) * C + lg * 8) * sizeof(TIN));
        noff[m][3] = (unsigned)(((bbase + nb.w) * C + lg * 8) * sizeof(TIN));
    }
    const char* hb = (const char*)hin;

    f32x4 acc[4][8];
#pragma unroll
    for (int m = 0; m < 4; ++m)
#pragma unroll
        for (int j = 0; j < 8; ++j) acc[m][j] = (f32x4){0.f, 0.f, 0.f, 0.f};

#pragma unroll
    for (int kk = 0; kk < K2 / 32; ++kk) {
        const int k0 = kk * 32;
        short8 a[4];
        if (k0 < C) {
            const unsigned kb = k0 * sizeof(TIN);
#pragma unroll
            for (int m = 0; m < 4; ++m)
                a[m] = frag_self((const TIN*)(hb + soff[m] + kb));
        } else {
            const unsigned kb = (k0 - C) * sizeof(TIN);
#pragma unroll
            for (int m = 0; m < 4; ++m)
                a[m] = frag_mean4((const TIN*)(hb + noff[m][0] + kb),
                                  (const TIN*)(hb + noff[m][1] + kb),
                                  (const TIN*)(hb + noff[m][2] + kb),
                                  (const TIN*)(hb + noff[m][3] + kb));
        }
#pragma unroll
        for (int j = 0; j < 8; ++j) {
            const int c = colb + j * 16 + lr;
            const short8 bf = *(const short8*)(
                Bs + ((c * ROWB + (k0 + lg * 8) * 2) ^ ((l & 7) << 4)));
#pragma unroll
            for (int m = 0; m < 4; ++m)
                acc[m][j] = __builtin_amdgcn_mfma_f32_16x16x32_bf16(a[m], bf, acc[m][j], 0, 0, 0);
        }
    }

#pragma unroll
    for (int j = 0; j < 8; ++j) {
        const int gcol = gcol0 + colb + j * 16 + lr;
        const float bv = bias[gcol];
#pragma unroll
        for (int m = 0; m < 4; ++m) {
#pragma unroll
            for (int r = 0; r < 4; ++r) {
                const int row = rowbase + m * 16 + lg * 4 + r;
                storev(out + (size_t)row * DOUT + gcol, fmaxf(acc[m][j][r] + bv, 0.f));
            }
        }
    }
}

extern "C" void kernel_launch(void* const* d_in, const int* in_sizes, int n_in,
                              void* d_out, int out_size, void* d_ws, size_t ws_size,
                              hipStream_t stream) {
    const float* x = (const float*)d_in[0];
    const int* nbr = (const int*)d_in[1];
    const float* Ws1 = (const float*)d_in[2];
    const float* Wn1 = (const float*)d_in[3];
    const float* b1 = (const float*)d_in[4];
    const float* Ws2 = (const float*)d_in[5];
    const float* Wn2 = (const float*)d_in[6];
    const float* b2 = (const float*)d_in[7];
    float* out = (float*)d_out;

    const int B = in_sizes[0] / (NNODES * 128);  // 4
    const int M = B * NNODES;                    // 221184

    char* ws = (char*)d_ws;
    const size_t h1_bytes = (size_t)M * DOUT * 2;
    const size_t hm_bytes = (size_t)M * DOUT * 2;  // xm for L1, then hm2 for L2
    const size_t need = h1_bytes + hm_bytes + 131072 + 262144;

    if (ws_size >= need) {
        unsigned short* h1 = (unsigned short*)ws;
        unsigned short* xm = (unsigned short*)(ws + h1_bytes);  // reused as hm2
        unsigned short* Wt1 = (unsigned short*)(ws + h1_bytes + hm_bytes);
        unsigned short* Wt2 = Wt1 + 256 * 256;

        build_wt<<<256, 256, 0, stream>>>(Ws1, Wn1, Wt1, 128);
        build_wt<<<512, 256, 0, stream>>>(Ws2, Wn2, Wt2, 256);

        hipFuncSetAttribute((const void*)sage_v13<8, unsigned short>,
                            hipFuncAttributeMaxDynamicSharedMemorySize, 65536);
        hipFuncSetAttribute((const void*)sage_v13<16, float>,
                            hipFuncAttributeMaxDynamicSharedMemorySize, 65536);

        const int nwg = (M / 128) * 2;  // 3456, divisible by 8

        // layer 1: xm = [bf16(x) | mean4(x)]; K2=256
        mean_xb<<<M / 16, 256, 0, stream>>>(x, nbr, xm);
        sage_v13<8, unsigned short>
            <<<nwg, 256, 65536, stream>>>(xm, xm, Wt1, b1, h1, nwg);
        // layer 2: hm2 overwrites xm; K2=512, A = h1 then hm
        mean_pass<256, unsigned short><<<M * 32 / 256, 256, 0, stream>>>(h1, nbr, xm);
        sage_v13<16, float>
            <<<nwg, 256, 65536, stream>>>(h1, xm, Wt2, b2, out, nwg);
    } else {
        unsigned short* h1 = (unsigned short*)ws;
        unsigned short* Wt1 = (unsigned short*)(ws + h1_bytes);
        unsigned short* Wt2 = Wt1 + 256 * 256;

        build_wt<<<256, 256, 0, stream>>>(Ws1, Wn1, Wt1, 128);
        build_wt<<<512, 256, 0, stream>>>(Ws2, Wn2, Wt2, 256);

        hipFuncSetAttribute((const void*)sage_v3<128, float, unsigned short>,
                            hipFuncAttributeMaxDynamicSharedMemorySize, 131072);
        hipFuncSetAttribute((const void*)sage_v3<256, unsigned short, float>,
                            hipFuncAttributeMaxDynamicSharedMemorySize, 131072);

        sage_v3<128, float, unsigned short>
            <<<dim3(M / 256, 1), 512, 131072, stream>>>(x, nbr, Wt1, b1, h1);
        sage_v3<256, unsigned short, float>
            <<<dim3(M / 512, 2), 512, 131072, stream>>>(h1, nbr, Wt2, b2, out);
    }
}

// Round 15
// 320.682 us; speedup vs baseline: 1.0963x; 1.0793x over previous
//
#include <hip/hip_runtime.h>
#include <stdint.h>

typedef __attribute__((ext_vector_type(8))) short short8;
typedef __attribute__((ext_vector_type(4))) float f32x4;

#define NNODES 55296
#define DOUT 256

#define WAIT_VM(N) asm volatile("s_waitcnt vmcnt(" #N ")" ::: "memory")
#define SOFT_FENCE asm volatile("" ::: "memory")

__device__ __forceinline__ float bf2f(unsigned short h) {
    union { unsigned u; float f; } x; x.u = ((unsigned)h) << 16; return x.f;
}
__device__ __forceinline__ unsigned short f2bf(float f) {
    union { float f; unsigned u; } x; x.f = f;
    return (unsigned short)((x.u + 0x7fffu + ((x.u >> 16) & 1u)) >> 16);
}

__device__ __forceinline__ void storev(float* p, float v) { *p = v; }
__device__ __forceinline__ void storev(unsigned short* p, float v) { *p = f2bf(v); }

__device__ __forceinline__ void dma16(const void* g, void* l) {
    __builtin_amdgcn_global_load_lds(
        reinterpret_cast<const unsigned int __attribute__((address_space(1)))*>((uintptr_t)g),
        reinterpret_cast<unsigned int __attribute__((address_space(3)))*>((uintptr_t)l),
        16, 0, 0);
}

// ---- fragment helpers (v3 fallback + mean kernels) ----
__device__ __forceinline__ short8 frag_self(const float* p) {
    float4 a = *(const float4*)p, b = *(const float4*)(p + 4);
    union { short8 s; unsigned short u[8]; } r;
    r.u[0] = f2bf(a.x); r.u[1] = f2bf(a.y); r.u[2] = f2bf(a.z); r.u[3] = f2bf(a.w);
    r.u[4] = f2bf(b.x); r.u[5] = f2bf(b.y); r.u[6] = f2bf(b.z); r.u[7] = f2bf(b.w);
    return r.s;
}
__device__ __forceinline__ short8 frag_self(const unsigned short* p) {
    return *(const short8*)p;
}
__device__ __forceinline__ void acc8(const float* p, float* o) {
    float4 a = *(const float4*)p, b = *(const float4*)(p + 4);
    o[0] += a.x; o[1] += a.y; o[2] += a.z; o[3] += a.w;
    o[4] += b.x; o[5] += b.y; o[6] += b.z; o[7] += b.w;
}
__device__ __forceinline__ void acc8(const unsigned short* p, float* o) {
    uint4 v = *(const uint4*)p;
    const unsigned short* u = (const unsigned short*)&v;
#pragma unroll
    for (int i = 0; i < 8; ++i) o[i] += bf2f(u[i]);
}
template <typename TIN>
__device__ __forceinline__ short8 frag_mean4(const TIN* p0, const TIN* p1,
                                             const TIN* p2, const TIN* p3) {
    float s[8] = {0.f, 0.f, 0.f, 0.f, 0.f, 0.f, 0.f, 0.f};
    acc8(p0, s); acc8(p1, s); acc8(p2, s); acc8(p3, s);
    union { short8 s8; unsigned short u[8]; } r;
#pragma unroll
    for (int i = 0; i < 8; ++i) r.u[i] = f2bf(s[i] * 0.25f);
    return r.s8;
}

// ---- old Wt (d-major) for v3 fallback ----
__global__ void build_wt(const float* __restrict__ Ws,
                         const float* __restrict__ Wn,
                         unsigned short* __restrict__ Wt, int C) {
    int K2 = 2 * C;
    int idx = blockIdx.x * 256 + threadIdx.x;
    if (idx >= 256 * K2) return;
    int d = idx / K2;
    int k = idx - d * K2;
    float v = (k < C) ? Ws[(size_t)k * DOUT + d] : Wn[(size_t)(k - C) * DOUT + d];
    Wt[idx] = f2bf(v);
}

// ---- pair-major pre-swizzled W: Wp[q][col 256][128B], byte kq ^ ((col&7)<<4) ----
__global__ void build_wt_pm(const float* __restrict__ Ws,
                            const float* __restrict__ Wn,
                            unsigned short* __restrict__ Wp, int C) {
    int K2 = 2 * C;
    int idx = blockIdx.x * 256 + threadIdx.x;
    if (idx >= 256 * K2) return;
    int d = idx / K2;
    int k = idx - d * K2;
    float v = (k < C) ? Ws[(size_t)k * DOUT + d] : Wn[(size_t)(k - C) * DOUT + d];
    int q = k >> 6;
    int kqb = (k & 63) * 2;
    int byte = q * 32768 + d * 128 + (kqb ^ ((d & 7) << 4));
    Wp[byte >> 1] = f2bf(v);
}

// ---- layer-1 prep (phase-major): xm_pm[c][M][32 elems]; c<4 self, c>=4 mean ----
__global__ __launch_bounds__(256) void mean_xb_pm(const float* __restrict__ x,
                                                  const int* __restrict__ nbr,
                                                  unsigned short* __restrict__ xm,
                                                  int mTot) {
    const int idx = blockIdx.x * 256 + threadIdx.x;
    const int node = idx >> 4;
    const int ch = (idx & 15) * 8;         // 0..120
    const int b = node / NNODES;
    const int n = node - b * NNODES;
    const size_t bbase = (size_t)b * NNODES;
    const int4 nb = *(const int4*)(nbr + (size_t)n * 4);
    const float* ps = x + (size_t)node * 128 + ch;
    union { uint4 v; unsigned short u[8]; } rs, rm;
    float4 a0 = *(const float4*)ps, a1 = *(const float4*)(ps + 4);
    rs.u[0] = f2bf(a0.x); rs.u[1] = f2bf(a0.y); rs.u[2] = f2bf(a0.z); rs.u[3] = f2bf(a0.w);
    rs.u[4] = f2bf(a1.x); rs.u[5] = f2bf(a1.y); rs.u[6] = f2bf(a1.z); rs.u[7] = f2bf(a1.w);
    float s[8] = {0.f, 0.f, 0.f, 0.f, 0.f, 0.f, 0.f, 0.f};
    acc8(x + (bbase + nb.x) * 128 + ch, s);
    acc8(x + (bbase + nb.y) * 128 + ch, s);
    acc8(x + (bbase + nb.z) * 128 + ch, s);
    acc8(x + (bbase + nb.w) * 128 + ch, s);
#pragma unroll
    for (int i = 0; i < 8; ++i) rm.u[i] = f2bf(s[i] * 0.25f);
    const size_t cs = (size_t)mTot * 32;
    *(uint4*)(xm + (size_t)(ch >> 5) * cs + (size_t)node * 32 + (ch & 31)) = rs.v;
    *(uint4*)(xm + (size_t)(4 + (ch >> 5)) * cs + (size_t)node * 32 + (ch & 31)) = rm.v;
}

// ---- hm_pm[c][M][32] = mean4 of h1_pm (phase-major in AND out) ----
__global__ __launch_bounds__(256) void mean_pass_pm(const unsigned short* __restrict__ h1,
                                                    const int* __restrict__ nbr,
                                                    unsigned short* __restrict__ hm,
                                                    int mTot) {
    const int idx = blockIdx.x * 256 + threadIdx.x;
    const int node = idx >> 5;
    const int ch = (idx & 31) * 8;         // 0..248
    const int b = node / NNODES;
    const int n = node - b * NNODES;
    const size_t bbase = (size_t)b * NNODES;
    const int4 nb = *(const int4*)(nbr + (size_t)n * 4);
    const size_t cs = (size_t)mTot * 32;
    const size_t co = (size_t)(ch >> 5) * cs + (ch & 31);
    float s[8] = {0.f, 0.f, 0.f, 0.f, 0.f, 0.f, 0.f, 0.f};
    acc8(h1 + co + (bbase + nb.x) * 32, s);
    acc8(h1 + co + (bbase + nb.y) * 32, s);
    acc8(h1 + co + (bbase + nb.z) * 32, s);
    acc8(h1 + co + (bbase + nb.w) * 32, s);
    union { uint4 v; unsigned short u[8]; } r;
#pragma unroll
    for (int i = 0; i < 8; ++i) r.u[i] = f2bf(s[i] * 0.25f);
    *(uint4*)(hm + co + (size_t)node * 32) = r.v;
}

// ============================================================================
// v14: v13 pipeline (identical barriers/vmcnt ladder) with CONTIGUOUS DMA:
//   A sources stored phase-major [chunk][M][64B] -> per-phase A slice for 128
//   rows is one contiguous 8KB block (2x 1KB instr/wave).
//   W stored pair-major pre-swizzled [q][col][128B] -> 16KB contiguous/pair.
//   LDS 64KB: W dbuf 2x16KB + A ring 4x8KB -> 2 blocks/CU.
//   Tile 128x128, 4 waves; XCD-chunked swizzle; MFMA swapped (wf, af).
// ============================================================================
template <int NK, typename TOUT>
__global__ __launch_bounds__(256) void sage_v14(
    const unsigned short* __restrict__ a0p,   // phase-major A, phases [0,8)
    const unsigned short* __restrict__ a1p,   // phase-major A, phases [8,16)
    const unsigned short* __restrict__ Wp,    // [NK/2 q][256 col][128B] pre-swz
    const float* __restrict__ bias,           // [256]
    TOUT* __restrict__ out,                   // h1_pm (bf16) or [M][256] f32
    int nwg, int mTot) {
    extern __shared__ char lds[];
    const int tid = threadIdx.x;
    const int bid = blockIdx.x;
    const int wk = (bid & 7) * (nwg >> 3) + (bid >> 3);  // bijective (nwg%8==0)
    const int yg = wk & 1;
    const int rb = wk >> 1;
    const int gcol0 = yg * 128;
    const int rowbase = rb * 128;

    const int l = tid & 63, w = tid >> 6;
    const int lr = l & 15, lg = l >> 4;
    const int rowg = w >> 1;          // 2 row groups x 64 rows
    const int colb = (w & 1) * 64;    // 2 col groups x 64 cols

    const size_t chstride = (size_t)mTot * 64;   // bytes per phase-chunk

    // W pair q -> wbuf (q&1): 16KB contiguous (4x 1KB instr/wave)
    auto stageW = [&](int q) {
        char* wb = lds + ((q & 1) << 14);
        const char* src = (const char*)Wp + (size_t)q * 32768 + (size_t)gcol0 * 128;
#pragma unroll
        for (int i = 0; i < 4; ++i) {
            int o = w * 4096 + i * 1024;
            dma16(src + o + l * 16, wb + o + l * 16);
        }
    };
    // A phase p -> ring (p&3): 8KB contiguous (2x 1KB instr/wave)
    auto issueA = [&](int p) {
        const char* base = (NK == 16 && p >= 8) ? (const char*)a1p : (const char*)a0p;
        const char* src = base + (size_t)(p & 7) * chstride + (size_t)rowbase * 64;
        char* ring = lds + 32768 + (p & 3) * 8192;
#pragma unroll
        for (int i = 0; i < 2; ++i) {
            int o = w * 2048 + i * 1024;
            dma16(src + o + l * 16, ring + o + l * 16);
        }
    };

    // prologue: W pair 0, A phases 0..2
    stageW(0); issueA(0); issueA(1); issueA(2);

    f32x4 acc[4][4];
#pragma unroll
    for (int m = 0; m < 4; ++m)
#pragma unroll
        for (int j = 0; j < 4; ++j) acc[m][j] = (f32x4){0.f, 0.f, 0.f, 0.f};

#pragma unroll
    for (int kk = 0; kk < NK; ++kk) {
        // exact outstanding-count wait (FIFO-derived, proven v13)
        int n;
        if (kk == 0) n = 4;
        else if (kk & 1) n = ((kk + 1 < NK) ? 6 : 0) + ((kk + 2 < NK) ? 2 : 0);
        else n = 2 + ((kk + 2 < NK) ? 2 : 0);
        switch (n) {
            case 0: WAIT_VM(0); break;
            case 2: WAIT_VM(2); break;
            case 4: WAIT_VM(4); break;
            case 6: WAIT_VM(6); break;
            default: WAIT_VM(8); break;
        }
        __builtin_amdgcn_s_barrier();
        SOFT_FENCE;

        if (((kk & 1) == 0) && (kk + 2 < NK)) stageW((kk + 2) >> 1);
        if (kk + 3 < NK) issueA(kk + 3);

        // af: A ring [row 128][64B]; row = (rowg*4+m)*16+lr, slot lg
        const int bufo = 32768 + (kk & 3) * 8192;
        short8 af[4];
#pragma unroll
        for (int m = 0; m < 4; ++m)
            af[m] = *(const short8*)(lds + bufo +
                                     ((rowg * 4 + m) * 16 + lr) * 64 + lg * 16);

        // wf: W buf [col 128][128B], pre-swizzled by ((col&7)<<4)
        char* wbuf = lds + (((kk >> 1) & 1) << 14);
        const int kq0 = ((kk & 1) << 6) | (lg << 4);
#pragma unroll
        for (int j = 0; j < 4; ++j) {
            const int col = colb + j * 16 + lr;
            const short8 wf = *(const short8*)(
                wbuf + (col << 7) + (kq0 ^ ((lr & 7) << 4)));
#pragma unroll
            for (int m = 0; m < 4; ++m)
                acc[m][j] = __builtin_amdgcn_mfma_f32_16x16x32_bf16(wf, af[m], acc[m][j], 0, 0, 0);
        }
        SOFT_FENCE;
    }

    // epilogue (swapped layout): lane holds 4 consecutive cols
#pragma unroll
    for (int m = 0; m < 4; ++m) {
        const int row = rowbase + rowg * 64 + m * 16 + lr;
#pragma unroll
        for (int j = 0; j < 4; ++j) {
            const int gcol = gcol0 + colb + j * 16 + lg * 4;
            const float4 bv = *(const float4*)(bias + gcol);
            float o0 = fmaxf(acc[m][j][0] + bv.x, 0.f);
            float o1 = fmaxf(acc[m][j][1] + bv.y, 0.f);
            float o2 = fmaxf(acc[m][j][2] + bv.z, 0.f);
            float o3 = fmaxf(acc[m][j][3] + bv.w, 0.f);
            if constexpr (sizeof(TOUT) == 4) {
                // final output: standard [M][256] f32
                float4 o = {o0, o1, o2, o3};
                *(float4*)((float*)out + (size_t)row * 256 + gcol) = o;
            } else {
                // h1: phase-major [chunk][M][32 elems] bf16
                union { unsigned short u[4]; uint2 v; } pk;
                pk.u[0] = f2bf(o0); pk.u[1] = f2bf(o1);
                pk.u[2] = f2bf(o2); pk.u[3] = f2bf(o3);
                unsigned short* hp = (unsigned short*)out +
                    (size_t)(gcol >> 5) * ((size_t)mTot * 32) +
                    (size_t)row * 32 + (gcol & 31);
                *(uint2*)hp = pk.v;
            }
        }
    }
}

// ---- v3 fallback (small ws): fused gather, weights all-K in LDS ----
template <int C, typename TIN, typename TOUT>
__global__ __launch_bounds__(512, 2) void sage_v3(
    const TIN* __restrict__ hin, const int* __restrict__ nbr,
    const unsigned short* __restrict__ Wt, const float* __restrict__ bias,
    TOUT* __restrict__ out) {
    constexpr int K2 = 2 * C;
    constexpr int ROWB = K2 * 2;
    constexpr int LCOLS = 131072 / ROWB;
    constexpr int CG = LCOLS / 128;
    constexpr int RG = 8 / CG;
    extern __shared__ char Bs[];

    const int tid = threadIdx.x;
    const int gcol0 = blockIdx.y * LCOLS;
    {
        const char* src = (const char*)(Wt + (size_t)gcol0 * K2);
#pragma unroll
        for (int i = 0; i < 16; ++i) {
            int byt = (i * 512 + tid) * 16;
            uint4 v = *(const uint4*)(src + byt);
            int c = byt / ROWB;
            *(uint4*)(Bs + (byt ^ ((c & 7) << 4))) = v;
        }
    }
    __syncthreads();

    const int l = tid & 63;
    const int w = tid >> 6;
    const int rowg = w / CG;
    const int colb = (w % CG) * 128;
    const int lr = l & 15, lg = l >> 4;

    const int rowbase = blockIdx.x * (RG * 64) + rowg * 64;
    const int bb = rowbase / NNODES;
    const int n0 = rowbase - bb * NNODES;
    const size_t bbase = (size_t)bb * NNODES;

    unsigned soff[4], noff[4][4];
#pragma unroll
    for (int m = 0; m < 4; ++m) {
        int r = m * 16 + lr;
        soff[m] = (unsigned)(((rowbase + r) * (size_t)C + lg * 8) * sizeof(TIN));
        int4 nb = *(const int4*)(nbr + (size_t)(n0 + r) * 4);
        noff[m][0] = (unsigned)(((bbase + nb.x) * C + lg * 8) * sizeof(TIN));
        noff[m][1] = (unsigned)(((bbase + nb.y) * C + lg * 8) * sizeof(TIN));
        noff[m][2] = (unsigned)(((bbase + nb.z) * C + lg * 8) * sizeof(TIN));
        noff[m][3] = (unsigned)(((bbase + nb.w) * C + lg * 8) * sizeof(TIN));
    }
    const char* hb = (const char*)hin;

    f32x4 acc[4][8];
#pragma unroll
    for (int m = 0; m < 4; ++m)
#pragma unroll
        for (int j = 0; j < 8; ++j) acc[m][j] = (f32x4){0.f, 0.f, 0.f, 0.f};

#pragma unroll
    for (int kk = 0; kk < K2 / 32; ++kk) {
        const int k0 = kk * 32;
        short8 a[4];
        if (k0 < C) {
            const unsigned kb = k0 * sizeof(TIN);
#pragma unroll
            for (int m = 0; m < 4; ++m)
                a[m] = frag_self((const TIN*)(hb + soff[m] + kb));
        } else {
            const unsigned kb = (k0 - C) * sizeof(TIN);
#pragma unroll
            for (int m = 0; m < 4; ++m)
                a[m] = frag_mean4((const TIN*)(hb + noff[m][0] + kb),
                                  (const TIN*)(hb + noff[m][1] + kb),
                                  (const TIN*)(hb + noff[m][2] + kb),
                                  (const TIN*)(hb + noff[m][3] + kb));
        }
#pragma unroll
        for (int j = 0; j < 8; ++j) {
            const int c = colb + j * 16 + lr;
            const short8 bf = *(const short8*)(
                Bs + ((c * ROWB + (k0 + lg * 8) * 2) ^ ((l & 7) << 4)));
#pragma unroll
            for (int m = 0; m < 4; ++m)
                acc[m][j] = __builtin_amdgcn_mfma_f32_16x16x32_bf16(a[m], bf, acc[m][j], 0, 0, 0);
        }
    }

#pragma unroll
    for (int j = 0; j < 8; ++j) {
        const int gcol = gcol0 + colb + j * 16 + lr;
        const float bv = bias[gcol];
#pragma unroll
        for (int m = 0; m < 4; ++m) {
#pragma unroll
            for (int r = 0; r < 4; ++r) {
                const int row = rowbase + m * 16 + lg * 4 + r;
                storev(out + (size_t)row * DOUT + gcol, fmaxf(acc[m][j][r] + bv, 0.f));
            }
        }
    }
}

extern "C" void kernel_launch(void* const* d_in, const int* in_sizes, int n_in,
                              void* d_out, int out_size, void* d_ws, size_t ws_size,
                              hipStream_t stream) {
    const float* x = (const float*)d_in[0];
    const int* nbr = (const int*)d_in[1];
    const float* Ws1 = (const float*)d_in[2];
    const float* Wn1 = (const float*)d_in[3];
    const float* b1 = (const float*)d_in[4];
    const float* Ws2 = (const float*)d_in[5];
    const float* Wn2 = (const float*)d_in[6];
    const float* b2 = (const float*)d_in[7];
    float* out = (float*)d_out;

    const int B = in_sizes[0] / (NNODES * 128);  // 4
    const int M = B * NNODES;                    // 221184

    char* ws = (char*)d_ws;
    const size_t h1_bytes = (size_t)M * DOUT * 2;
    const size_t hm_bytes = (size_t)M * DOUT * 2;  // xm_pm for L1, then hm_pm for L2
    const size_t need = h1_bytes + hm_bytes + 131072 + 262144;

    if (ws_size >= need) {
        unsigned short* h1 = (unsigned short*)ws;                       // phase-major
        unsigned short* xm = (unsigned short*)(ws + h1_bytes);          // pm; reused hm
        unsigned short* W1p = (unsigned short*)(ws + h1_bytes + hm_bytes);
        unsigned short* W2p = W1p + 256 * 256;

        build_wt_pm<<<256, 256, 0, stream>>>(Ws1, Wn1, W1p, 128);
        build_wt_pm<<<512, 256, 0, stream>>>(Ws2, Wn2, W2p, 256);

        hipFuncSetAttribute((const void*)sage_v14<8, unsigned short>,
                            hipFuncAttributeMaxDynamicSharedMemorySize, 65536);
        hipFuncSetAttribute((const void*)sage_v14<16, float>,
                            hipFuncAttributeMaxDynamicSharedMemorySize, 65536);

        const int nwg = (M / 128) * 2;  // 3456, divisible by 8

        // layer 1: xm_pm = [bf16(x) | mean4(x)] phase-major; K2=256 GEMM
        mean_xb_pm<<<M / 16, 256, 0, stream>>>(x, nbr, xm, M);
        sage_v14<8, unsigned short>
            <<<nwg, 256, 65536, stream>>>(xm, xm, W1p, b1, h1, nwg, M);
        // layer 2: hm_pm overwrites xm; K2=512 GEMM (A = h1_pm then hm_pm)
        mean_pass_pm<<<M / 8, 256, 0, stream>>>(h1, nbr, xm, M);
        sage_v14<16, float>
            <<<nwg, 256, 65536, stream>>>(h1, xm, W2p, b2, out, nwg, M);
    } else {
        unsigned short* h1 = (unsigned short*)ws;
        unsigned short* Wt1 = (unsigned short*)(ws + h1_bytes);
        unsigned short* Wt2 = Wt1 + 256 * 256;

        build_wt<<<256, 256, 0, stream>>>(Ws1, Wn1, Wt1, 128);
        build_wt<<<512, 256, 0, stream>>>(Ws2, Wn2, Wt2, 256);

        hipFuncSetAttribute((const void*)sage_v3<128, float, unsigned short>,
                            hipFuncAttributeMaxDynamicSharedMemorySize, 131072);
        hipFuncSetAttribute((const void*)sage_v3<256, unsigned short, float>,
                            hipFuncAttributeMaxDynamicSharedMemorySize, 131072);

        sage_v3<128, float, unsigned short>
            <<<dim3(M / 256, 1), 512, 131072, stream>>>(x, nbr, Wt1, b1, h1);
        sage_v3<256, unsigned short, float>
            <<<dim3(M / 512, 2), 512, 131072, stream>>>(h1, nbr, Wt2, b2, out);
    }
}

// Round 16
// 315.702 us; speedup vs baseline: 1.1136x; 1.0158x over previous
//
#include <hip/hip_runtime.h>
#include <stdint.h>

typedef __attribute__((ext_vector_type(8))) short short8;
typedef __attribute__((ext_vector_type(4))) float f32x4;

#define NNODES 55296
#define DOUT 256

#define WAIT_VM(N) asm volatile("s_waitcnt vmcnt(" #N ")" ::: "memory")
#define SOFT_FENCE asm volatile("" ::: "memory")

__device__ __forceinline__ float bf2f(unsigned short h) {
    union { unsigned u; float f; } x; x.u = ((unsigned)h) << 16; return x.f;
}
__device__ __forceinline__ unsigned short f2bf(float f) {
    union { float f; unsigned u; } x; x.f = f;
    return (unsigned short)((x.u + 0x7fffu + ((x.u >> 16) & 1u)) >> 16);
}

__device__ __forceinline__ void storev(float* p, float v) { *p = v; }
__device__ __forceinline__ void storev(unsigned short* p, float v) { *p = f2bf(v); }

__device__ __forceinline__ void dma16(const void* g, void* l) {
    __builtin_amdgcn_global_load_lds(
        reinterpret_cast<const unsigned int __attribute__((address_space(1)))*>((uintptr_t)g),
        reinterpret_cast<unsigned int __attribute__((address_space(3)))*>((uintptr_t)l),
        16, 0, 0);
}

// ---- fragment helpers (v3 fallback + mean kernels) ----
__device__ __forceinline__ short8 frag_self(const float* p) {
    float4 a = *(const float4*)p, b = *(const float4*)(p + 4);
    union { short8 s; unsigned short u[8]; } r;
    r.u[0] = f2bf(a.x); r.u[1] = f2bf(a.y); r.u[2] = f2bf(a.z); r.u[3] = f2bf(a.w);
    r.u[4] = f2bf(b.x); r.u[5] = f2bf(b.y); r.u[6] = f2bf(b.z); r.u[7] = f2bf(b.w);
    return r.s;
}
__device__ __forceinline__ short8 frag_self(const unsigned short* p) {
    return *(const short8*)p;
}
__device__ __forceinline__ void acc8(const float* p, float* o) {
    float4 a = *(const float4*)p, b = *(const float4*)(p + 4);
    o[0] += a.x; o[1] += a.y; o[2] += a.z; o[3] += a.w;
    o[4] += b.x; o[5] += b.y; o[6] += b.z; o[7] += b.w;
}
__device__ __forceinline__ void acc8(const unsigned short* p, float* o) {
    uint4 v = *(const uint4*)p;
    const unsigned short* u = (const unsigned short*)&v;
#pragma unroll
    for (int i = 0; i < 8; ++i) o[i] += bf2f(u[i]);
}
template <typename TIN>
__device__ __forceinline__ short8 frag_mean4(const TIN* p0, const TIN* p1,
                                             const TIN* p2, const TIN* p3) {
    float s[8] = {0.f, 0.f, 0.f, 0.f, 0.f, 0.f, 0.f, 0.f};
    acc8(p0, s); acc8(p1, s); acc8(p2, s); acc8(p3, s);
    union { short8 s8; unsigned short u[8]; } r;
#pragma unroll
    for (int i = 0; i < 8; ++i) r.u[i] = f2bf(s[i] * 0.25f);
    return r.s8;
}

// ---- old Wt (d-major) for v3 fallback ----
__global__ void build_wt(const float* __restrict__ Ws,
                         const float* __restrict__ Wn,
                         unsigned short* __restrict__ Wt, int C) {
    int K2 = 2 * C;
    int idx = blockIdx.x * 256 + threadIdx.x;
    if (idx >= 256 * K2) return;
    int d = idx / K2;
    int k = idx - d * K2;
    float v = (k < C) ? Ws[(size_t)k * DOUT + d] : Wn[(size_t)(k - C) * DOUT + d];
    Wt[idx] = f2bf(v);
}

// ---- pair-major pre-swizzled W: Wp[q][col 256][128B], byte kq ^ ((col&7)<<4) ----
__global__ void build_wt_pm(const float* __restrict__ Ws,
                            const float* __restrict__ Wn,
                            unsigned short* __restrict__ Wp, int C) {
    int K2 = 2 * C;
    int idx = blockIdx.x * 256 + threadIdx.x;
    if (idx >= 256 * K2) return;
    int d = idx / K2;
    int k = idx - d * K2;
    float v = (k < C) ? Ws[(size_t)k * DOUT + d] : Wn[(size_t)(k - C) * DOUT + d];
    int q = k >> 6;
    int kqb = (k & 63) * 2;
    int byte = q * 32768 + d * 128 + (kqb ^ ((d & 7) << 4));
    Wp[byte >> 1] = f2bf(v);
}

// ---- layer-1 prep (phase-major): xm_pm[c][M][32 elems]; c<4 self, c>=4 mean ----
__global__ __launch_bounds__(256) void mean_xb_pm(const float* __restrict__ x,
                                                  const int* __restrict__ nbr,
                                                  unsigned short* __restrict__ xm,
                                                  int mTot) {
    const int idx = blockIdx.x * 256 + threadIdx.x;
    const int node = idx >> 4;
    const int ch = (idx & 15) * 8;         // 0..120
    const int b = node / NNODES;
    const int n = node - b * NNODES;
    const size_t bbase = (size_t)b * NNODES;
    const int4 nb = *(const int4*)(nbr + (size_t)n * 4);
    const float* ps = x + (size_t)node * 128 + ch;
    union { uint4 v; unsigned short u[8]; } rs, rm;
    float4 a0 = *(const float4*)ps, a1 = *(const float4*)(ps + 4);
    rs.u[0] = f2bf(a0.x); rs.u[1] = f2bf(a0.y); rs.u[2] = f2bf(a0.z); rs.u[3] = f2bf(a0.w);
    rs.u[4] = f2bf(a1.x); rs.u[5] = f2bf(a1.y); rs.u[6] = f2bf(a1.z); rs.u[7] = f2bf(a1.w);
    float s[8] = {0.f, 0.f, 0.f, 0.f, 0.f, 0.f, 0.f, 0.f};
    acc8(x + (bbase + nb.x) * 128 + ch, s);
    acc8(x + (bbase + nb.y) * 128 + ch, s);
    acc8(x + (bbase + nb.z) * 128 + ch, s);
    acc8(x + (bbase + nb.w) * 128 + ch, s);
#pragma unroll
    for (int i = 0; i < 8; ++i) rm.u[i] = f2bf(s[i] * 0.25f);
    const size_t cs = (size_t)mTot * 32;
    *(uint4*)(xm + (size_t)(ch >> 5) * cs + (size_t)node * 32 + (ch & 31)) = rs.v;
    *(uint4*)(xm + (size_t)(4 + (ch >> 5)) * cs + (size_t)node * 32 + (ch & 31)) = rm.v;
}

// ---- hm_pm[c][M][32] = mean4 of h1_pm (phase-major in AND out) ----
__global__ __launch_bounds__(256) void mean_pass_pm(const unsigned short* __restrict__ h1,
                                                    const int* __restrict__ nbr,
                                                    unsigned short* __restrict__ hm,
                                                    int mTot) {
    const int idx = blockIdx.x * 256 + threadIdx.x;
    const int node = idx >> 5;
    const int ch = (idx & 31) * 8;         // 0..248
    const int b = node / NNODES;
    const int n = node - b * NNODES;
    const size_t bbase = (size_t)b * NNODES;
    const int4 nb = *(const int4*)(nbr + (size_t)n * 4);
    const size_t cs = (size_t)mTot * 32;
    const size_t co = (size_t)(ch >> 5) * cs + (ch & 31);
    float s[8] = {0.f, 0.f, 0.f, 0.f, 0.f, 0.f, 0.f, 0.f};
    acc8(h1 + co + (bbase + nb.x) * 32, s);
    acc8(h1 + co + (bbase + nb.y) * 32, s);
    acc8(h1 + co + (bbase + nb.z) * 32, s);
    acc8(h1 + co + (bbase + nb.w) * 32, s);
    union { uint4 v; unsigned short u[8]; } r;
#pragma unroll
    for (int i = 0; i < 8; ++i) r.u[i] = f2bf(s[i] * 0.25f);
    *(uint4*)(hm + co + (size_t)node * 32) = r.v;
}

// ============================================================================
// v15: v14 with K=64 phases (half the barriers). NK = K2/64 phases.
//   W: dbuf 2x16KB; W(p) = Wp[q=p] slice (16KB contiguous), staged 1 phase
//      ahead (W is L2-resident after first touch -> short latency need).
//   A: ring 3x16KB; phase p = chunks {2p, 2p+1} (2x 8KB contiguous), staged
//      2 phases ahead (~2600 cy cover).
//   Uniform vmcnt(4) (FIFO: only A(p+1) newer than required W(p)); 0 at end.
//   LDS 80KB -> 2 blocks/CU. Tile 128x128, 4 waves; XCD swizzle; MFMA (wf,af).
// ============================================================================
template <int NK, typename TOUT>
__global__ __launch_bounds__(256) void sage_v15(
    const unsigned short* __restrict__ a0p,   // phase-major A chunks [0,8)
    const unsigned short* __restrict__ a1p,   // phase-major A chunks [8,16)
    const unsigned short* __restrict__ Wp,    // [NK q][256 col][128B] pre-swz
    const float* __restrict__ bias,           // [256]
    TOUT* __restrict__ out,                   // h1_pm (bf16) or [M][256] f32
    int nwg, int mTot) {
    extern __shared__ char lds[];
    const int tid = threadIdx.x;
    const int bid = blockIdx.x;
    const int wk = (bid & 7) * (nwg >> 3) + (bid >> 3);  // bijective (nwg%8==0)
    const int yg = wk & 1;
    const int rb = wk >> 1;
    const int gcol0 = yg * 128;
    const int rowbase = rb * 128;

    const int l = tid & 63, w = tid >> 6;
    const int lr = l & 15, lg = l >> 4;
    const int rowg = w >> 1;          // 2 row groups x 64 rows
    const int colb = (w & 1) * 64;    // 2 col groups x 64 cols

    const size_t chstride = (size_t)mTot * 64;   // bytes per K32 chunk

    // W phase p -> wbuf (p&1): 16KB contiguous (4x 1KB instr/wave)
    auto stageW = [&](int p) {
        char* wb = lds + ((p & 1) << 14);
        const char* src = (const char*)Wp + (size_t)p * 32768 + (size_t)gcol0 * 128;
#pragma unroll
        for (int i = 0; i < 4; ++i) {
            int o = w * 4096 + i * 1024;
            dma16(src + o + l * 16, wb + o + l * 16);
        }
    };
    // A phase p (chunks 2p,2p+1) -> ring (p%3): 2x 8KB contiguous
    auto issueA = [&](int p) {
        const char* base = (p >= 4) ? (const char*)a1p : (const char*)a0p;
        const char* src = base + (size_t)((2 * p) & 7) * chstride + (size_t)rowbase * 64;
        char* ring = lds + 32768 + (p % 3) * 16384;
#pragma unroll
        for (int s = 0; s < 2; ++s) {
            const char* cs_ = src + (size_t)s * chstride;
            char* dst = ring + s * 8192;
#pragma unroll
            for (int i = 0; i < 2; ++i) {
                int o = w * 2048 + i * 1024;
                dma16(cs_ + o + l * 16, dst + o + l * 16);
            }
        }
    };

    // prologue: W0, A0, A1
    stageW(0); issueA(0); issueA(1);

    f32x4 acc[4][4];
#pragma unroll
    for (int m = 0; m < 4; ++m)
#pragma unroll
        for (int j = 0; j < 4; ++j) acc[m][j] = (f32x4){0.f, 0.f, 0.f, 0.f};

#pragma unroll
    for (int kk = 0; kk < NK; ++kk) {
        if (kk == NK - 1) { WAIT_VM(0); } else { WAIT_VM(4); }
        __builtin_amdgcn_s_barrier();
        SOFT_FENCE;

        if (kk + 1 < NK) stageW(kk + 1);
        if (kk + 2 < NK) issueA(kk + 2);

        const int ringo = 32768 + (kk % 3) * 16384;
        char* wbuf = lds + ((kk & 1) << 14);
#pragma unroll
        for (int sub = 0; sub < 2; ++sub) {
            short8 af[4];
#pragma unroll
            for (int m = 0; m < 4; ++m)
                af[m] = *(const short8*)(lds + ringo + sub * 8192 +
                                         ((rowg * 4 + m) * 16 + lr) * 64 + lg * 16);
            const int kq0 = (sub << 6) | (lg << 4);
#pragma unroll
            for (int j = 0; j < 4; ++j) {
                const int col = colb + j * 16 + lr;
                const short8 wf = *(const short8*)(
                    wbuf + (col << 7) + (kq0 ^ ((lr & 7) << 4)));
#pragma unroll
                for (int m = 0; m < 4; ++m)
                    acc[m][j] = __builtin_amdgcn_mfma_f32_16x16x32_bf16(wf, af[m], acc[m][j], 0, 0, 0);
            }
        }
        SOFT_FENCE;
    }

    // epilogue (swapped layout): lane holds 4 consecutive cols
#pragma unroll
    for (int m = 0; m < 4; ++m) {
        const int row = rowbase + rowg * 64 + m * 16 + lr;
#pragma unroll
        for (int j = 0; j < 4; ++j) {
            const int gcol = gcol0 + colb + j * 16 + lg * 4;
            const float4 bv = *(const float4*)(bias + gcol);
            float o0 = fmaxf(acc[m][j][0] + bv.x, 0.f);
            float o1 = fmaxf(acc[m][j][1] + bv.y, 0.f);
            float o2 = fmaxf(acc[m][j][2] + bv.z, 0.f);
            float o3 = fmaxf(acc[m][j][3] + bv.w, 0.f);
            if constexpr (sizeof(TOUT) == 4) {
                float4 o = {o0, o1, o2, o3};
                *(float4*)((float*)out + (size_t)row * 256 + gcol) = o;
            } else {
                union { unsigned short u[4]; uint2 v; } pk;
                pk.u[0] = f2bf(o0); pk.u[1] = f2bf(o1);
                pk.u[2] = f2bf(o2); pk.u[3] = f2bf(o3);
                unsigned short* hp = (unsigned short*)out +
                    (size_t)(gcol >> 5) * ((size_t)mTot * 32) +
                    (size_t)row * 32 + (gcol & 31);
                *(uint2*)hp = pk.v;
            }
        }
    }
}

// ---- v3 fallback (small ws): fused gather, weights all-K in LDS ----
template <int C, typename TIN, typename TOUT>
__global__ __launch_bounds__(512, 2) void sage_v3(
    const TIN* __restrict__ hin, const int* __restrict__ nbr,
    const unsigned short* __restrict__ Wt, const float* __restrict__ bias,
    TOUT* __restrict__ out) {
    constexpr int K2 = 2 * C;
    constexpr int ROWB = K2 * 2;
    constexpr int LCOLS = 131072 / ROWB;
    constexpr int CG = LCOLS / 128;
    constexpr int RG = 8 / CG;
    extern __shared__ char Bs[];

    const int tid = threadIdx.x;
    const int gcol0 = blockIdx.y * LCOLS;
    {
        const char* src = (const char*)(Wt + (size_t)gcol0 * K2);
#pragma unroll
        for (int i = 0; i < 16; ++i) {
            int byt = (i * 512 + tid) * 16;
            uint4 v = *(const uint4*)(src + byt);
            int c = byt / ROWB;
            *(uint4*)(Bs + (byt ^ ((c & 7) << 4))) = v;
        }
    }
    __syncthreads();

    const int l = tid & 63;
    const int w = tid >> 6;
    const int rowg = w / CG;
    const int colb = (w % CG) * 128;
    const int lr = l & 15, lg = l >> 4;

    const int rowbase = blockIdx.x * (RG * 64) + rowg * 64;
    const int bb = rowbase / NNODES;
    const int n0 = rowbase - bb * NNODES;
    const size_t bbase = (size_t)bb * NNODES;

    unsigned soff[4], noff[4][4];
#pragma unroll
    for (int m = 0; m < 4; ++m) {
        int r = m * 16 + lr;
        soff[m] = (unsigned)(((rowbase + r) * (size_t)C + lg * 8) * sizeof(TIN));
        int4 nb = *(const int4*)(nbr + (size_t)(n0 + r) * 4);
        noff[m][0] = (unsigned)(((bbase + nb.x) * C + lg * 8) * sizeof(TIN));
        noff[m][1] = (unsigned)(((bbase + nb.y) * C + lg * 8) * sizeof(TIN));
        noff[m][2] = (unsigned)(((bbase + nb.z) * C + lg * 8) * sizeof(TIN));
        noff[m][3] = (unsigned)(((bbase + nb.w) * C + lg * 8) * sizeof(TIN));
    }
    const char* hb = (const char*)hin;

    f32x4 acc[4][8];
#pragma unroll
    for (int m = 0; m < 4; ++m)
#pragma unroll
        for (int j = 0; j < 8; ++j) acc[m][j] = (f32x4){0.f, 0.f, 0.f, 0.f};

#pragma unroll
    for (int kk = 0; kk < K2 / 32; ++kk) {
        const int k0 = kk * 32;
        short8 a[4];
        if (k0 < C) {
            const unsigned kb = k0 * sizeof(TIN);
#pragma unroll
            for (int m = 0; m < 4; ++m)
                a[m] = frag_self((const TIN*)(hb + soff[m] + kb));
        } else {
            const unsigned kb = (k0 - C) * sizeof(TIN);
#pragma unroll
            for (int m = 0; m < 4; ++m)
                a[m] = frag_mean4((const TIN*)(hb + noff[m][0] + kb),
                                  (const TIN*)(hb + noff[m][1] + kb),
                                  (const TIN*)(hb + noff[m][2] + kb),
                                  (const TIN*)(hb + noff[m][3] + kb));
        }
#pragma unroll
        for (int j = 0; j < 8; ++j) {
            const int c = colb + j * 16 + lr;
            const short8 bf = *(const short8*)(
                Bs + ((c * ROWB + (k0 + lg * 8) * 2) ^ ((l & 7) << 4)));
#pragma unroll
            for (int m = 0; m < 4; ++m)
                acc[m][j] = __builtin_amdgcn_mfma_f32_16x16x32_bf16(a[m], bf, acc[m][j], 0, 0, 0);
        }
    }

#pragma unroll
    for (int j = 0; j < 8; ++j) {
        const int gcol = gcol0 + colb + j * 16 + lr;
        const float bv = bias[gcol];
#pragma unroll
        for (int m = 0; m < 4; ++m) {
#pragma unroll
            for (int r = 0; r < 4; ++r) {
                const int row = rowbase + m * 16 + lg * 4 + r;
                storev(out + (size_t)row * DOUT + gcol, fmaxf(acc[m][j][r] + bv, 0.f));
            }
        }
    }
}

extern "C" void kernel_launch(void* const* d_in, const int* in_sizes, int n_in,
                              void* d_out, int out_size, void* d_ws, size_t ws_size,
                              hipStream_t stream) {
    const float* x = (const float*)d_in[0];
    const int* nbr = (const int*)d_in[1];
    const float* Ws1 = (const float*)d_in[2];
    const float* Wn1 = (const float*)d_in[3];
    const float* b1 = (const float*)d_in[4];
    const float* Ws2 = (const float*)d_in[5];
    const float* Wn2 = (const float*)d_in[6];
    const float* b2 = (const float*)d_in[7];
    float* out = (float*)d_out;

    const int B = in_sizes[0] / (NNODES * 128);  // 4
    const int M = B * NNODES;                    // 221184

    char* ws = (char*)d_ws;
    const size_t h1_bytes = (size_t)M * DOUT * 2;
    const size_t hm_bytes = (size_t)M * DOUT * 2;  // xm_pm for L1, then hm_pm for L2
    const size_t need = h1_bytes + hm_bytes + 131072 + 262144;

    if (ws_size >= need) {
        unsigned short* h1 = (unsigned short*)ws;                       // phase-major
        unsigned short* xm = (unsigned short*)(ws + h1_bytes);          // pm; reused hm
        unsigned short* W1p = (unsigned short*)(ws + h1_bytes + hm_bytes);
        unsigned short* W2p = W1p + 256 * 256;

        build_wt_pm<<<256, 256, 0, stream>>>(Ws1, Wn1, W1p, 128);
        build_wt_pm<<<512, 256, 0, stream>>>(Ws2, Wn2, W2p, 256);

        hipFuncSetAttribute((const void*)sage_v15<4, unsigned short>,
                            hipFuncAttributeMaxDynamicSharedMemorySize, 81920);
        hipFuncSetAttribute((const void*)sage_v15<8, float>,
                            hipFuncAttributeMaxDynamicSharedMemorySize, 81920);

        const int nwg = (M / 128) * 2;  // 3456, divisible by 8

        // layer 1: xm_pm = [bf16(x) | mean4(x)] phase-major; K2=256 GEMM (4 phases)
        mean_xb_pm<<<M / 16, 256, 0, stream>>>(x, nbr, xm, M);
        sage_v15<4, unsigned short>
            <<<nwg, 256, 81920, stream>>>(xm, xm, W1p, b1, h1, nwg, M);
        // layer 2: hm_pm overwrites xm; K2=512 GEMM (8 phases, A = h1_pm then hm_pm)
        mean_pass_pm<<<M / 8, 256, 0, stream>>>(h1, nbr, xm, M);
        sage_v15<8, float>
            <<<nwg, 256, 81920, stream>>>(h1, xm, W2p, b2, out, nwg, M);
    } else {
        unsigned short* h1 = (unsigned short*)ws;
        unsigned short* Wt1 = (unsigned short*)(ws + h1_bytes);
        unsigned short* Wt2 = Wt1 + 256 * 256;

        build_wt<<<256, 256, 0, stream>>>(Ws1, Wn1, Wt1, 128);
        build_wt<<<512, 256, 0, stream>>>(Ws2, Wn2, Wt2, 256);

        hipFuncSetAttribute((const void*)sage_v3<128, float, unsigned short>,
                            hipFuncAttributeMaxDynamicSharedMemorySize, 131072);
        hipFuncSetAttribute((const void*)sage_v3<256, unsigned short, float>,
                            hipFuncAttributeMaxDynamicSharedMemorySize, 131072);

        sage_v3<128, float, unsigned short>
            <<<dim3(M / 256, 1), 512, 131072, stream>>>(x, nbr, Wt1, b1, h1);
        sage_v3<256, unsigned short, float>
            <<<dim3(M / 512, 2), 512, 131072, stream>>>(h1, nbr, Wt2, b2, out);
    }
}